// Round 4
// baseline (84.029 us; speedup 1.0000x reference)
//
#include <hip/hip_runtime.h>

typedef float f32x4 __attribute__((ext_vector_type(4)));
typedef _Float16 half8 __attribute__((ext_vector_type(8)));

#define NEG 0.2f

// ---------------------------------------------------------------------------
// K1: Wh = nf @ W^T (f32), s1 = Wh@a1, s2 = Wh@a2 (exact f32),
//     per-block max(s2) -> smax slots, Wh -> fp16 transposed [b][o][j].
// grid 256 = 8 batches x 32 row-blocks of 64 rows; block 256 (4 waves).
// ---------------------------------------------------------------------------
__global__ __launch_bounds__(256) void gat_wh_kernel(
    const float* __restrict__ nf, const float* __restrict__ W,
    const float* __restrict__ a, _Float16* __restrict__ whT,
    float* __restrict__ s1g, float* __restrict__ s2g, float* __restrict__ smax)
{
    const int b    = blockIdx.x >> 5;
    const int rb   = blockIdx.x & 31;
    const int row0 = rb * 64;
    const int t    = threadIdx.x;
    const int lane = t & 63;
    const int wv   = t >> 6;

    __shared__ _Float16 whL[64][72];   // [row][o], pad to 72 to spread banks
    __shared__ float    wred[4];

    // W row (o = lane) in registers: 64 VGPRs
    f32x4 Wreg[16];
    const float* wp = W + lane * 64;
#pragma unroll
    for (int i = 0; i < 16; ++i) Wreg[i] = *(const f32x4*)(wp + i * 4);
    const float a1v = a[lane];
    const float a2v = a[64 + lane];

    const float* nfb = nf + ((long)b * 2048 + row0) * 64;
    float wmax = -3.0e38f;

    for (int g = 0; g < 16; ++g) {
        const int row = g * 4 + wv;
        const f32x4* nfp = (const f32x4*)(nfb + row * 64);  // same addr across wave -> broadcast
        f32x4 acc = {0.f, 0.f, 0.f, 0.f};
#pragma unroll
        for (int i = 0; i < 16; ++i) acc += nfp[i] * Wreg[i];
        const float wh = acc.x + acc.y + acc.z + acc.w;     // Wh[row][lane]
        whL[row][lane] = (_Float16)wh;
        float p1 = wh * a1v;
        float p2 = wh * a2v;
#pragma unroll
        for (int m = 32; m >= 1; m >>= 1) {
            p1 += __shfl_xor(p1, m);
            p2 += __shfl_xor(p2, m);
        }
        if (lane == 0) {
            s1g[b * 2048 + row0 + row] = p1;
            s2g[b * 2048 + row0 + row] = p2;
            wmax = fmaxf(wmax, p2);
        }
    }
    if (lane == 0) wred[wv] = wmax;
    __syncthreads();
    if (t == 0)
        smax[blockIdx.x] = fmaxf(fmaxf(wred[0], wred[1]), fmaxf(wred[2], wred[3]));

    // transpose out: whT[(b*64+o)*2048 + row0 + j]
    const int o = t >> 2;
    const int part = t & 3;
    unsigned int tmp[8];
#pragma unroll
    for (int kk = 0; kk < 8; ++kk) {
        const int j = part * 16 + kk * 2;
        unsigned int lo = *(const unsigned short*)&whL[j][o];
        unsigned int hi = *(const unsigned short*)&whL[j + 1][o];
        tmp[kk] = lo | (hi << 16);
    }
    uint4 v0, v1;
    v0.x = tmp[0]; v0.y = tmp[1]; v0.z = tmp[2]; v0.w = tmp[3];
    v1.x = tmp[4]; v1.y = tmp[5]; v1.z = tmp[6]; v1.w = tmp[7];
    _Float16* dst = whT + ((long)(b * 64 + o) * 2048 + row0 + part * 16);
    *(uint4*)dst = v0;
    *(uint4*)(dst + 8) = v1;
}

// ---------------------------------------------------------------------------
// K1.5: per-row softmax denominators. m2_b = max_j s2 (from smax slots),
//       M_i = lrelu(s1_i + m2_b), iD_i = 1/sum_j exp(lrelu(s1_i+s2_j)-M_i).
// grid 512 = 8 batches x 16 blocks of 32 rows; block 256.
// ---------------------------------------------------------------------------
__global__ __launch_bounds__(256) void gat_denom_kernel(
    const float* __restrict__ s1g, const float* __restrict__ s2g,
    const float* __restrict__ smax, float* __restrict__ m2g,
    float* __restrict__ iDg)
{
    const int b  = blockIdx.x >> 6;
    const int i0 = (blockIdx.x & 63) * 32;
    const int t  = threadIdx.x;

    __shared__ __attribute__((aligned(16))) float s2sh[2048];
    __shared__ float m2sh;

#pragma unroll
    for (int k = 0; k < 8; ++k) s2sh[t + k * 256] = s2g[b * 2048 + t + k * 256];
    if (t < 32) {
        float v = smax[b * 32 + t];
#pragma unroll
        for (int m = 16; m >= 1; m >>= 1) v = fmaxf(v, __shfl_xor(v, m));
        if (t == 0) m2sh = v;
    }
    __syncthreads();

    const float m2  = m2sh;
    const int   r   = t >> 3, q = t & 7;
    const float s1r = s1g[b * 2048 + i0 + r];
    const float xm  = s1r + m2;
    const float M   = fmaxf(xm, NEG * xm);
    float acc = 0.f;
    for (int j = q; j < 2048; j += 8) {
        float x = s1r + s2sh[j];
        float e = fmaxf(x, NEG * x);
        acc += __expf(e - M);
    }
    acc += __shfl_xor(acc, 1);
    acc += __shfl_xor(acc, 2);
    acc += __shfl_xor(acc, 4);
    if (q == 0) iDg[b * 2048 + i0 + r] = 1.0f / acc;
    if ((blockIdx.x & 63) == 0 && t == 0) m2g[b] = m2;
}

// ---------------------------------------------------------------------------
// K2: fused roles, ZERO barriers, ZERO LDS.
//   blocks 0..255   (PV role):  wave owns 16 rows x all 64 out-cols.
//     A-fragments (P) computed in-register (8 exps/lane/K-step, no dup),
//     B fragments straight from L2-resident whT, 4x mfma per K-step.
//   blocks 256..2303 (store role): pure streaming attention write.
//     f32x4 per lane -> 1KB/wave contiguous nontemporal stores.
// ---------------------------------------------------------------------------
__global__ __launch_bounds__(256) void gat_main_kernel(
    const _Float16* __restrict__ whT, const float* __restrict__ s1g,
    const float* __restrict__ s2g, const float* __restrict__ m2g,
    const float* __restrict__ iDg, float* __restrict__ outp)
{
    const int t    = threadIdx.x;
    const int lane = t & 63;
    const int wv   = t >> 6;

    if (blockIdx.x < 256) {
        // ---------------- PV role ----------------
        const int b  = blockIdx.x >> 5;
        const int i0 = (blockIdx.x & 31) * 64 + wv * 16;
        const int q  = lane & 15;
        const int g  = lane >> 4;
        const int row = i0 + q;

        const float s1r = s1g[b * 2048 + row];
        const float m2  = m2g[b];
        const float xm  = s1r + m2;
        const float Mr  = fmaxf(xm, NEG * xm);
        const float iDr = iDg[b * 2048 + row];

        const float*    s2p = s2g + b * 2048 + g * 8;
        const _Float16* B0  = whT + ((long)(b * 64 + q)) * 2048 + g * 8;

        f32x4 acc0 = {0.f,0.f,0.f,0.f}, acc1 = {0.f,0.f,0.f,0.f};
        f32x4 acc2 = {0.f,0.f,0.f,0.f}, acc3 = {0.f,0.f,0.f,0.f};

        for (int kk = 0; kk < 64; ++kk) {
            const int j0 = kk * 32;
            half8 b0 = *(const half8*)(B0 + j0);
            half8 b1 = *(const half8*)(B0 + 16 * 2048 + j0);
            half8 b2 = *(const half8*)(B0 + 32 * 2048 + j0);
            half8 b3 = *(const half8*)(B0 + 48 * 2048 + j0);

            f32x4 sa = *(const f32x4*)(s2p + j0);
            f32x4 sb = *(const f32x4*)(s2p + j0 + 4);
            half8 a;
#pragma unroll
            for (int e = 0; e < 4; ++e) {
                float x  = s1r + sa[e];
                float lr = fmaxf(x, NEG * x);
                a[e] = (_Float16)(__expf(lr - Mr) * iDr);
                float y  = s1r + sb[e];
                float lq = fmaxf(y, NEG * y);
                a[e + 4] = (_Float16)(__expf(lq - Mr) * iDr);
            }
            acc0 = __builtin_amdgcn_mfma_f32_16x16x32_f16(a, b0, acc0, 0, 0, 0);
            acc1 = __builtin_amdgcn_mfma_f32_16x16x32_f16(a, b1, acc1, 0, 0, 0);
            acc2 = __builtin_amdgcn_mfma_f32_16x16x32_f16(a, b2, acc2, 0, 0, 0);
            acc3 = __builtin_amdgcn_mfma_f32_16x16x32_f16(a, b3, acc3, 0, 0, 0);
        }

        // epilogue: elu; C/D layout col=lane&15, row=g*4+reg
        float* ob = outp + ((long)(b * 2048 + i0 + g * 4)) * 64 + q;
#pragma unroll
        for (int r = 0; r < 4; ++r) {
            float x0 = acc0[r], x1 = acc1[r], x2 = acc2[r], x3 = acc3[r];
            ob[(long)r * 64]      = (x0 > 0.f) ? x0 : (__expf(x0) - 1.0f);
            ob[(long)r * 64 + 16] = (x1 > 0.f) ? x1 : (__expf(x1) - 1.0f);
            ob[(long)r * 64 + 32] = (x2 > 0.f) ? x2 : (__expf(x2) - 1.0f);
            ob[(long)r * 64 + 48] = (x3 > 0.f) ? x3 : (__expf(x3) - 1.0f);
        }
    } else {
        // ---------------- store role ----------------
        const int sb = blockIdx.x - 256;
        const int b  = sb >> 8;
        const int r0 = (sb & 255) * 8 + wv * 2;

        const float* s2b = s2g + b * 2048;
        const float  m2  = m2g[b];
        float* attnb = outp + 1048576 + ((long)b * 2048 + r0) * 2048;

#pragma unroll
        for (int rr = 0; rr < 2; ++rr) {
            const int row  = r0 + rr;
            const float s1r = s1g[b * 2048 + row];
            const float xm  = s1r + m2;
            const float Mr  = fmaxf(xm, NEG * xm);
            const float iDr = iDg[b * 2048 + row];
            float* arow = attnb + (long)rr * 2048;
#pragma unroll
            for (int cc = 0; cc < 8; ++cc) {
                const int j = cc * 256 + lane * 4;
                f32x4 s = *(const f32x4*)(s2b + j);
                f32x4 p;
#pragma unroll
                for (int e = 0; e < 4; ++e) {
                    float x  = s1r + s[e];
                    float lr = fmaxf(x, NEG * x);
                    p[e] = __expf(lr - Mr) * iDr;
                }
                __builtin_nontemporal_store(p, (f32x4*)(arow + j));
            }
        }
    }
}

extern "C" void kernel_launch(void* const* d_in, const int* in_sizes, int n_in,
                              void* d_out, int out_size, void* d_ws, size_t ws_size,
                              hipStream_t stream)
{
    (void)in_sizes; (void)n_in; (void)out_size; (void)ws_size;
    const float* nf = (const float*)d_in[0];
    const float* W  = (const float*)d_in[1];
    const float* a  = (const float*)d_in[2];
    float* outp = (float*)d_out;

    char* ws = (char*)d_ws;
    _Float16* whT = (_Float16*)ws;                     // 2 MB: [8][64][2048] fp16
    float* s1g  = (float*)(ws + 2097152);              // 64 KB
    float* s2g  = (float*)(ws + 2162688);              // 64 KB
    float* smax = (float*)(ws + 2228224);              // 1 KB (256 slots)
    float* m2g  = (float*)(ws + 2229248);              // 32 B (8 slots)
    float* iDg  = (float*)(ws + 2230272);              // 64 KB

    gat_wh_kernel<<<256, 256, 0, stream>>>(nf, W, a, whT, s1g, s2g, smax);
    gat_denom_kernel<<<512, 256, 0, stream>>>(s1g, s2g, smax, m2g, iDg);
    gat_main_kernel<<<2304, 256, 0, stream>>>(whT, s1g, s2g, m2g, iDg, outp);
}